// Round 10
// baseline (596.875 us; speedup 1.0000x reference)
//
#include <hip/hip_runtime.h>

#define HD 32    // hidden/emb dim
#define ND 16    // node feature dim
#define ED 8     // edge feature dim
#define NPART 8  // one partition per XCD (blockIdx & 7 -> XCD round-robin)
#define NCH 16   // edge-stream chunks per partition
#define MAXCSV 12544  // max ceil(NV/NPART) supported by LDS histogram
#define MAXCSA 640    // max ceil(NA/NPART)

// ---------------- bf16 pack/unpack helpers ----------------
__device__ __forceinline__ unsigned bf16rne(float f) {
    unsigned u = __float_as_uint(f);
    return (u + 0x7fffu + ((u >> 16) & 1u)) >> 16;
}
__device__ __forceinline__ unsigned packbf2(float lo, float hi) {
    return bf16rne(lo) | (bf16rne(hi) << 16);
}
__device__ __forceinline__ void unpack8(uint4 r, float* p) {
    p[0] = __uint_as_float(r.x << 16); p[1] = __uint_as_float(r.x & 0xffff0000u);
    p[2] = __uint_as_float(r.y << 16); p[3] = __uint_as_float(r.y & 0xffff0000u);
    p[4] = __uint_as_float(r.z << 16); p[5] = __uint_as_float(r.z & 0xffff0000u);
    p[6] = __uint_as_float(r.w << 16); p[7] = __uint_as_float(r.w & 0xffff0000u);
}

// ===========================================================================
// Standalone channel-parallel precompute (no dependence on CSR).
//  PXg[v]=gvb1+xv.gvW1[0:16] (f32)   PXh[v] (f32)   PXga[a] (f32)
//  PCg16[c]=bf16(xc.gvW1[16:32])     PAh16[a]=bf16(xa.hvW1[16:32])
//  Mg=gvW2@fvW1[16:48], bg; Mh,bh; Mga=gaW2@faW1[16:48], bga;
//  Nfv=fvW2@gaW1[16:48], bfv
// ===========================================================================
__global__ __launch_bounds__(256) void precompC_kernel(
    const float* __restrict__ xv, const float* __restrict__ xc, const float* __restrict__ xa,
    const float* __restrict__ gvW1, const float* __restrict__ gvb1,
    const float* __restrict__ hvW1, const float* __restrict__ hvb1,
    const float* __restrict__ gaW1, const float* __restrict__ gab1,
    const float* __restrict__ gvW2, const float* __restrict__ gvb2,
    const float* __restrict__ hvW2, const float* __restrict__ hvb2,
    const float* __restrict__ gaW2, const float* __restrict__ gab2,
    const float* __restrict__ fvW1, const float* __restrict__ fvW2,
    const float* __restrict__ fvb2, const float* __restrict__ faW1,
    float* __restrict__ PXg, float* __restrict__ PXh, float* __restrict__ PXga,
    unsigned* __restrict__ PCg16, unsigned* __restrict__ PAh16,
    float* __restrict__ Mg, float* __restrict__ bg,
    float* __restrict__ Mh, float* __restrict__ bh,
    float* __restrict__ Mga, float* __restrict__ bga,
    float* __restrict__ Nfv, float* __restrict__ bfv,
    int nV, int nC, int nA)
{
    int bV = (nV * 32 + 255) / 256, bC = (nC * 32 + 255) / 256, bA = (nA * 32 + 255) / 256;
    int b = blockIdx.x;
    int tid = threadIdx.x;
    int ch = tid & 31;
    __shared__ float s0[512], s1[512];

    if (b < bV) {                        // ---- PXg, PXh (f32) ----
        for (int i = tid; i < 512; i += 256) { s0[i] = gvW1[i]; s1[i] = hvW1[i]; }
        __syncthreads();
        int v = (b * 256 + tid) >> 5;
        if (v >= nV) return;
        float x = (ch < ND) ? xv[(size_t)v * ND + ch] : 0.f;
        float pg = gvb1[ch], ph = hvb1[ch];
#pragma unroll
        for (int i = 0; i < ND; i++) {
            float xi = __shfl(x, i, 32);
            pg = fmaf(xi, s0[i * 32 + ch], pg);
            ph = fmaf(xi, s1[i * 32 + ch], ph);
        }
        PXg[(size_t)v * 32 + ch] = pg;
        PXh[(size_t)v * 32 + ch] = ph;
    } else if (b < bV + bC) {            // ---- PCg16 (bf16) ----
        for (int i = tid; i < 512; i += 256) s0[i] = gvW1[512 + i];
        __syncthreads();
        int c = ((b - bV) * 256 + tid) >> 5;
        if (c >= nC) return;
        float x = (ch < ND) ? xc[(size_t)c * ND + ch] : 0.f;
        float p = 0.f;
#pragma unroll
        for (int i = 0; i < ND; i++) p = fmaf(__shfl(x, i, 32), s0[i * 32 + ch], p);
        float hi = __shfl_xor(p, 1, 32);
        if (!(ch & 1)) PCg16[(size_t)c * 16 + (ch >> 1)] = packbf2(p, hi);
    } else if (b < bV + bC + bA) {       // ---- PAh16 (bf16), PXga (f32) ----
        for (int i = tid; i < 512; i += 256) { s0[i] = hvW1[512 + i]; s1[i] = gaW1[i]; }
        __syncthreads();
        int a = ((b - bV - bC) * 256 + tid) >> 5;
        if (a >= nA) return;
        float x = (ch < ND) ? xa[(size_t)a * ND + ch] : 0.f;
        float ph = 0.f, pg = gab1[ch];
#pragma unroll
        for (int i = 0; i < ND; i++) {
            float xi = __shfl(x, i, 32);
            ph = fmaf(xi, s0[i * 32 + ch], ph);
            pg = fmaf(xi, s1[i * 32 + ch], pg);
        }
        float hi = __shfl_xor(ph, 1, 32);
        if (!(ch & 1)) PAh16[(size_t)a * 16 + (ch >> 1)] = packbf2(ph, hi);
        PXga[(size_t)a * 32 + ch] = pg;
    } else {                             // ---- folded layer-2 matrices ----
        int m = b - (bV + bC + bA);
        const float *W2, *b2, *T; float *M, *bb; int toff;
        if (m == 0)      { W2 = gvW2; b2 = gvb2; T = fvW1; toff = ND;      M = Mg;  bb = bg;  }
        else if (m == 1) { W2 = hvW2; b2 = hvb2; T = fvW1; toff = ND + HD; M = Mh;  bb = bh;  }
        else if (m == 2) { W2 = gaW2; b2 = gab2; T = faW1; toff = ND;      M = Mga; bb = bga; }
        else             { W2 = fvW2; b2 = fvb2; T = gaW1; toff = ND;      M = Nfv; bb = bfv; }
        for (int idx = tid; idx < 1024; idx += 256) {
            int c = idx >> 5, h = idx & 31;
            float s = 0.f;
#pragma unroll
            for (int o = 0; o < HD; o++) s = fmaf(W2[c * HD + o], T[(toff + o) * HD + h], s);
            M[idx] = s;
        }
        if (tid < HD) {
            int h = tid;
            float s = 0.f;
#pragma unroll
            for (int o = 0; o < HD; o++) s = fmaf(b2[o], T[(toff + o) * HD + h], s);
            bb[h] = s;
        }
    }
}

// ===========================================================================
// Pass A: atomic-free per-(partition,chunk) LDS histogram.
// grid = 256: bid = list*128 + chunk*8 + part.  list 0: c2v_t -> cnt_g.
// list 1: a2v_t -> cnt_h AND a2v_s -> cnt_a (one stream read, two counts).
// ===========================================================================
__global__ __launch_bounds__(256) void countP_kernel(
    const int* __restrict__ c2v_t, int* __restrict__ cnt_g, int nEC,
    const int* __restrict__ a2v_t, const int* __restrict__ a2v_s,
    int* __restrict__ cnt_h, int* __restrict__ cnt_a, int nEA,
    int csizeV, int csizeA)
{
    __shared__ int lcnt[MAXCSV + MAXCSA];
    int b = blockIdx.x;
    int part  = b & (NPART - 1);
    int chunk = (b >> 3) & (NCH - 1);
    int list  = b >> 7;
    int tid = threadIdx.x;
    int loV = part * csizeV, loA = part * csizeA;

    if (list == 0) {
        for (int i = tid; i < csizeV; i += 256) lcnt[i] = 0;
        __syncthreads();
        int i0 = (int)(((long long)chunk * nEC) / NCH);
        int i1 = (int)(((long long)(chunk + 1) * nEC) / NCH);
        for (int i = i0 + tid; i < i1; i += 256) {
            int t = c2v_t[i];
            if ((unsigned)(t - loV) < (unsigned)csizeV) atomicAdd(&lcnt[t - loV], 1);
        }
        __syncthreads();
        int* out = cnt_g + (size_t)(part * NCH + chunk) * csizeV;
        for (int i = tid; i < csizeV; i += 256) out[i] = lcnt[i];
    } else {
        for (int i = tid; i < csizeV + csizeA; i += 256) lcnt[i] = 0;
        __syncthreads();
        int i0 = (int)(((long long)chunk * nEA) / NCH);
        int i1 = (int)(((long long)(chunk + 1) * nEA) / NCH);
        for (int i = i0 + tid; i < i1; i += 256) {
            int t = a2v_t[i];
            int s = a2v_s[i];
            if ((unsigned)(t - loV) < (unsigned)csizeV) atomicAdd(&lcnt[t - loV], 1);
            if ((unsigned)(s - loA) < (unsigned)csizeA) atomicAdd(&lcnt[csizeV + s - loA], 1);
        }
        __syncthreads();
        int* outh = cnt_h + (size_t)(part * NCH + chunk) * csizeV;
        for (int i = tid; i < csizeV; i += 256) outh[i] = lcnt[i];
        int* outa = cnt_a + (size_t)(part * NCH + chunk) * csizeA;
        for (int i = tid; i < csizeA; i += 256) outa[i] = lcnt[csizeV + i];
    }
}

// deg[v] = sum over chunks of cnt[(p*NCH+c)*csize + idx]
__global__ __launch_bounds__(256) void degsum_kernel(
    const int* __restrict__ cnt_g, const int* __restrict__ cnt_h,
    const int* __restrict__ cnt_a,
    int* __restrict__ deg_g, int* __restrict__ deg_h, int* __restrict__ deg_a,
    int nV, int nA, int csizeV, int csizeA)
{
    int i = blockIdx.x * 256 + threadIdx.x;
    const int* cnt; int* deg; int csize, idx0;
    if (i < nV)                { cnt = cnt_g; deg = deg_g; csize = csizeV; idx0 = i; }
    else if (i < 2 * nV)       { cnt = cnt_h; deg = deg_h; csize = csizeV; idx0 = i - nV; }
    else if (i < 2 * nV + nA)  { cnt = cnt_a; deg = deg_a; csize = csizeA; idx0 = i - 2 * nV; }
    else return;
    int p = idx0 / csize, idx = idx0 - p * csize;
    const int* base = cnt + (size_t)(p * NCH) * csize + idx;
    int s = 0;
#pragma unroll
    for (int c = 0; c < NCH; c++) s += base[(size_t)c * csize];
    deg[idx0] = s;
}

// in-place: cnt[(p*NCH+c)*csize + idx] <- off[v] + prefix over chunks
__global__ __launch_bounds__(256) void chunkbase_kernel(
    int* __restrict__ cnt_g, int* __restrict__ cnt_h, int* __restrict__ cnt_a,
    const int* __restrict__ off_g, const int* __restrict__ off_h,
    const int* __restrict__ off_a,
    int nV, int nA, int csizeV, int csizeA)
{
    int i = blockIdx.x * 256 + threadIdx.x;
    int* cnt; const int* off; int csize, idx0;
    if (i < nV)                { cnt = cnt_g; off = off_g; csize = csizeV; idx0 = i; }
    else if (i < 2 * nV)       { cnt = cnt_h; off = off_h; csize = csizeV; idx0 = i - nV; }
    else if (i < 2 * nV + nA)  { cnt = cnt_a; off = off_a; csize = csizeA; idx0 = i - 2 * nV; }
    else return;
    int p = idx0 / csize, idx = idx0 - p * csize;
    int* base = cnt + (size_t)(p * NCH) * csize + idx;
    int running = off[idx0];
#pragma unroll
    for (int c = 0; c < NCH; c++) {
        int t = base[(size_t)c * csize];
        base[(size_t)c * csize] = running;
        running += t;
    }
}

// pass 1 (fused over 3 arrays): per-1024-chunk sums
__global__ __launch_bounds__(256) void scan_p1f(
    const int* __restrict__ dg, const int* __restrict__ dh, const int* __restrict__ da,
    int* __restrict__ cg, int* __restrict__ chs, int* __restrict__ ca,
    int nV, int nA, int chunksV)
{
    int b = blockIdx.x;
    const int* in; int* cs; int n; int c;
    if (b < chunksV)            { in = dg; cs = cg;  n = nV; c = b; }
    else if (b < 2 * chunksV)   { in = dh; cs = chs; n = nV; c = b - chunksV; }
    else                        { in = da; cs = ca;  n = nA; c = b - 2 * chunksV; }

    int i0 = c * 1024 + threadIdx.x * 4;
    int s = 0;
#pragma unroll
    for (int j = 0; j < 4; j++) { int i = i0 + j; if (i < n) s += in[i]; }
#pragma unroll
    for (int m = 1; m < 64; m <<= 1) s += __shfl_xor(s, m, 64);
    __shared__ int ws[4];
    if ((threadIdx.x & 63) == 0) ws[threadIdx.x >> 6] = s;
    __syncthreads();
    if (threadIdx.x == 0) cs[c] = ws[0] + ws[1] + ws[2] + ws[3];
}

__device__ __forceinline__ void exscan_block(int* __restrict__ c, int n)
{
    int i = threadIdx.x;
    int v = (i < n) ? c[i] : 0;
    int x = v;
    int lane = i & 63, wid = i >> 6;
#pragma unroll
    for (int dd = 1; dd < 64; dd <<= 1) {
        int y = __shfl_up(x, dd, 64);
        if (lane >= dd) x += y;
    }
    __shared__ int ws[16];
    if (lane == 63) ws[wid] = x;
    __syncthreads();
    if (i == 0) {
        int a = 0;
#pragma unroll
        for (int w = 0; w < 16; w++) { int t = ws[w]; ws[w] = a; a += t; }
    }
    __syncthreads();
    int excl = ws[wid] + x - v;
    if (i < n) c[i] = excl;
}

__global__ __launch_bounds__(1024) void scan_p2(
    int* c0, int n0, int* c1, int n1, int* c2, int n2)
{
    if (blockIdx.x == 0)      exscan_block(c0, n0);
    else if (blockIdx.x == 1) exscan_block(c1, n1);
    else                      exscan_block(c2, n2);
}

__global__ __launch_bounds__(1024) void scan_p3f(
    const int* __restrict__ dg, const int* __restrict__ dh, const int* __restrict__ da,
    const int* __restrict__ cg, const int* __restrict__ chs, const int* __restrict__ ca,
    int* __restrict__ og, int* __restrict__ oh, int* __restrict__ oa,
    int nV, int nA, int chunksV)
{
    int b = blockIdx.x;
    const int* deg; const int* cbase; int* off; int n; int c;
    if (b < chunksV)          { deg = dg; cbase = cg;  off = og; n = nV; c = b; }
    else if (b < 2 * chunksV) { deg = dh; cbase = chs; off = oh; n = nV; c = b - chunksV; }
    else                      { deg = da; cbase = ca;  off = oa; n = nA; c = b - 2 * chunksV; }

    int i = c * 1024 + threadIdx.x;
    int v = (i < n) ? deg[i] : 0;
    int x = v;
    int lane = threadIdx.x & 63, wid = threadIdx.x >> 6;
#pragma unroll
    for (int dd = 1; dd < 64; dd <<= 1) {
        int y = __shfl_up(x, dd, 64);
        if (lane >= dd) x += y;
    }
    __shared__ int ws[16];
    if (lane == 63) ws[wid] = x;
    __syncthreads();
    if (threadIdx.x == 0) {
        int a = 0;
#pragma unroll
        for (int w = 0; w < 16; w++) { int t = ws[w]; ws[w] = a; a += t; }
    }
    __syncthreads();
    int excl = cbase[c] + ws[wid] + x - v;
    if (i < n) off[i] = excl;
}

// ===========================================================================
// Pass B: atomic-free scatter. Same (list, part, chunk) decomposition as
// pass A; per-block write bases loaded into LDS, slots assigned via LDS
// atomics, slot stores contiguous per partition (XCD-local). No global
// atomics anywhere.
// ===========================================================================
__global__ __launch_bounds__(256) void scatterB_kernel(
    const int* __restrict__ c2v_t, const int* __restrict__ c2v_s,
    const int* __restrict__ cnt_g, int2* __restrict__ slot_g, int nEC,
    const int* __restrict__ a2v_t, const int* __restrict__ a2v_s,
    const int* __restrict__ cnt_h, const int* __restrict__ cnt_a,
    int2* __restrict__ slot_h, int2* __restrict__ slot_a, int nEA,
    int csizeV, int csizeA)
{
    __shared__ int lbase[MAXCSV + MAXCSA];
    int b = blockIdx.x;
    int part  = b & (NPART - 1);
    int chunk = (b >> 3) & (NCH - 1);
    int list  = b >> 7;
    int tid = threadIdx.x;
    int loV = part * csizeV, loA = part * csizeA;

    if (list == 0) {
        const int* src = cnt_g + (size_t)(part * NCH + chunk) * csizeV;
        for (int i = tid; i < csizeV; i += 256) lbase[i] = src[i];
        __syncthreads();
        int i0 = (int)(((long long)chunk * nEC) / NCH);
        int i1 = (int)(((long long)(chunk + 1) * nEC) / NCH);
        for (int i = i0 + tid; i < i1; i += 256) {
            int t = c2v_t[i];
            if ((unsigned)(t - loV) < (unsigned)csizeV) {
                int p = atomicAdd(&lbase[t - loV], 1);
                slot_g[p] = make_int2(c2v_s[i], i);
            }
        }
    } else {
        const int* srch = cnt_h + (size_t)(part * NCH + chunk) * csizeV;
        for (int i = tid; i < csizeV; i += 256) lbase[i] = srch[i];
        const int* srca = cnt_a + (size_t)(part * NCH + chunk) * csizeA;
        for (int i = tid; i < csizeA; i += 256) lbase[csizeV + i] = srca[i];
        __syncthreads();
        int i0 = (int)(((long long)chunk * nEA) / NCH);
        int i1 = (int)(((long long)(chunk + 1) * nEA) / NCH);
        for (int i = i0 + tid; i < i1; i += 256) {
            int t = a2v_t[i];
            int s = a2v_s[i];
            if ((unsigned)(t - loV) < (unsigned)csizeV) {
                int p = atomicAdd(&lbase[t - loV], 1);
                slot_h[p] = make_int2(s, i);
            }
            if ((unsigned)(s - loA) < (unsigned)csizeA) {
                int q = atomicAdd(&lbase[csizeV + s - loA], 1);
                slot_a[q] = make_int2(t, i);
            }
        }
    }
}

// ===========================================================================
// fv edge kernel: 8 lanes per variable node, lane = edge-slot.
// slot = {src, eid}; gather ea via eid; gather bf16 partial row via src.
// acc[ch] += relu(PX[ch] + P*[src][ch] + ea . W[last 8 rows][ch])
// ===========================================================================
__global__ __launch_bounds__(256) void fv_edge_kernel(
    const float* __restrict__ PXg, const unsigned* __restrict__ PCg16,
    const float* __restrict__ PXh, const unsigned* __restrict__ PAh16,
    const int2* __restrict__ slot_g, const int2* __restrict__ slot_h,
    const float* __restrict__ ea_c, const float* __restrict__ ea_a,
    const int* __restrict__ off_g, const int* __restrict__ deg_g,
    const int* __restrict__ off_h, const int* __restrict__ deg_h,
    const float* __restrict__ gvW1, const float* __restrict__ hvW1,
    float* __restrict__ Ag, float* __restrict__ Ah, int nV)
{
    int gid = blockIdx.x * 256 + threadIdx.x;
    int v   = gid >> 3;
    int sub = threadIdx.x & 7;
    if (v >= nV) return;

    float px[HD], acc[HD];

    // ---------------- g: c2v edges ----------------
    {
        const float4* pp = reinterpret_cast<const float4*>(PXg + (size_t)v * HD);
#pragma unroll
        for (int q = 0; q < 8; q++) {
            float4 t = pp[q];
            px[4*q+0] = t.x; px[4*q+1] = t.y; px[4*q+2] = t.z; px[4*q+3] = t.w;
        }
#pragma unroll
        for (int ch = 0; ch < HD; ch++) acc[ch] = 0.f;

        int base = off_g[v], d = deg_g[v];
        for (int k = sub; k < d; k += 8) {
            int2 w = slot_g[base + k];
            int s = w.x, e = w.y;
            const uint4* pr = reinterpret_cast<const uint4*>(PCg16 + (size_t)s * 16);
            uint4 r0 = pr[0], r1 = pr[1], r2 = pr[2], r3 = pr[3];
            const float4* pe = reinterpret_cast<const float4*>(ea_c + (size_t)e * ED);
            float4 q0 = pe[0], q1 = pe[1];
            float pc[HD], ev[ED];
            unpack8(r0, pc + 0); unpack8(r1, pc + 8);
            unpack8(r2, pc + 16); unpack8(r3, pc + 24);
            ev[0]=q0.x; ev[1]=q0.y; ev[2]=q0.z; ev[3]=q0.w;
            ev[4]=q1.x; ev[5]=q1.y; ev[6]=q1.z; ev[7]=q1.w;
#pragma unroll
            for (int ch = 0; ch < HD; ch++) {
                float t = px[ch] + pc[ch];
#pragma unroll
                for (int i = 0; i < ED; i++) t = fmaf(ev[i], gvW1[(2 * ND + i) * HD + ch], t);
                acc[ch] += fmaxf(t, 0.f);
            }
        }
#pragma unroll
        for (int m = 1; m < 8; m <<= 1) {
#pragma unroll
            for (int ch = 0; ch < HD; ch++) acc[ch] += __shfl_xor(acc[ch], m, 64);
        }
        if (sub == 0) {
            float4* dst = reinterpret_cast<float4*>(Ag + (size_t)v * HD);
#pragma unroll
            for (int q = 0; q < 8; q++)
                dst[q] = make_float4(acc[4*q+0], acc[4*q+1], acc[4*q+2], acc[4*q+3]);
        }
    }

    // ---------------- h: a2v edges ----------------
    {
        const float4* pp = reinterpret_cast<const float4*>(PXh + (size_t)v * HD);
#pragma unroll
        for (int q = 0; q < 8; q++) {
            float4 t = pp[q];
            px[4*q+0] = t.x; px[4*q+1] = t.y; px[4*q+2] = t.z; px[4*q+3] = t.w;
        }
#pragma unroll
        for (int ch = 0; ch < HD; ch++) acc[ch] = 0.f;

        int base = off_h[v], d = deg_h[v];
        for (int k = sub; k < d; k += 8) {
            int2 w = slot_h[base + k];
            int s = w.x, e = w.y;
            const uint4* pr = reinterpret_cast<const uint4*>(PAh16 + (size_t)s * 16);
            uint4 r0 = pr[0], r1 = pr[1], r2 = pr[2], r3 = pr[3];
            const float4* pe = reinterpret_cast<const float4*>(ea_a + (size_t)e * ED);
            float4 q0 = pe[0], q1 = pe[1];
            float pc[HD], ev[ED];
            unpack8(r0, pc + 0); unpack8(r1, pc + 8);
            unpack8(r2, pc + 16); unpack8(r3, pc + 24);
            ev[0]=q0.x; ev[1]=q0.y; ev[2]=q0.z; ev[3]=q0.w;
            ev[4]=q1.x; ev[5]=q1.y; ev[6]=q1.z; ev[7]=q1.w;
#pragma unroll
            for (int ch = 0; ch < HD; ch++) {
                float t = px[ch] + pc[ch];
#pragma unroll
                for (int i = 0; i < ED; i++) t = fmaf(ev[i], hvW1[(2 * ND + i) * HD + ch], t);
                acc[ch] += fmaxf(t, 0.f);
            }
        }
#pragma unroll
        for (int m = 1; m < 8; m <<= 1) {
#pragma unroll
            for (int ch = 0; ch < HD; ch++) acc[ch] += __shfl_xor(acc[ch], m, 64);
        }
        if (sub == 0) {
            float4* dst = reinterpret_cast<float4*>(Ah + (size_t)v * HD);
#pragma unroll
            for (int q = 0; q < 8; q++)
                dst[q] = make_float4(acc[4*q+0], acc[4*q+1], acc[4*q+2], acc[4*q+3]);
        }
    }
}

// ===========================================================================
// fv node kernel, CHANNEL-PARALLEL: thread = (v, ch).
// hid = relu(fvb1 + xv.fvW1[0:16] + [dg>0]bg + [dh>0]bh + Ag.Mg/dg + Ah.Mh/dh)
// PFga16[v] = bf16(bfv + hid . Nfv)
// ===========================================================================
__global__ __launch_bounds__(256) void fv_node_kernel(
    const float* __restrict__ xv,
    const float* __restrict__ Ag, const float* __restrict__ Ah,
    const int* __restrict__ deg_g, const int* __restrict__ deg_h,
    const float* __restrict__ fvW1, const float* __restrict__ fvb1,
    const float* __restrict__ Mg, const float* __restrict__ bg,
    const float* __restrict__ Mh, const float* __restrict__ bh,
    const float* __restrict__ Nfv, const float* __restrict__ bfv,
    unsigned* __restrict__ PFga16, int nV)
{
    __shared__ float sMg[1024], sMh[1024], sN[1024], sF[512];
    __shared__ float sbg[32], sbh[32], sbf[32], sb1[32];
    for (int i = threadIdx.x; i < 1024; i += 256) {
        sMg[i] = Mg[i]; sMh[i] = Mh[i]; sN[i] = Nfv[i];
    }
    for (int i = threadIdx.x; i < 512; i += 256) sF[i] = fvW1[i];
    if (threadIdx.x < 32) {
        sbg[threadIdx.x] = bg[threadIdx.x];
        sbh[threadIdx.x] = bh[threadIdx.x];
        sbf[threadIdx.x] = bfv[threadIdx.x];
        sb1[threadIdx.x] = fvb1[threadIdx.x];
    }
    __syncthreads();

    int gid = blockIdx.x * 256 + threadIdx.x;
    int v = gid >> 5, ch = threadIdx.x & 31;
    if (v >= nV) return;

    float x = (ch < ND) ? xv[(size_t)v * ND + ch] : 0.f;
    float t = sb1[ch];
#pragma unroll
    for (int i = 0; i < ND; i++) t = fmaf(__shfl(x, i, 32), sF[i * 32 + ch], t);

    float agr[HD], ahr[HD];
    {
        const float4* pg4 = reinterpret_cast<const float4*>(Ag + (size_t)v * HD);
        const float4* ph4 = reinterpret_cast<const float4*>(Ah + (size_t)v * HD);
#pragma unroll
        for (int q = 0; q < 8; q++) {
            float4 a = pg4[q];
            agr[4*q+0] = a.x; agr[4*q+1] = a.y; agr[4*q+2] = a.z; agr[4*q+3] = a.w;
            float4 b = ph4[q];
            ahr[4*q+0] = b.x; ahr[4*q+1] = b.y; ahr[4*q+2] = b.z; ahr[4*q+3] = b.w;
        }
    }
    float sg = 0.f, sh = 0.f;
#pragma unroll
    for (int c = 0; c < HD; c++) {
        sg = fmaf(agr[c], sMg[c * 32 + ch], sg);
        sh = fmaf(ahr[c], sMh[c * 32 + ch], sh);
    }
    int dg = deg_g[v], dh = deg_h[v];
    float invg = dg > 0 ? 1.f / (float)dg : 0.f;
    float invh = dh > 0 ? 1.f / (float)dh : 0.f;
    t += (dg > 0 ? sbg[ch] : 0.f) + (dh > 0 ? sbh[ch] : 0.f) + invg * sg + invh * sh;
    float hid = fmaxf(t, 0.f);

    float pf = sbf[ch];
#pragma unroll
    for (int h = 0; h < HD; h++) pf = fmaf(__shfl(hid, h, 32), sN[h * 32 + ch], pf);
    float hi = __shfl_xor(pf, 1, 32);
    if (!(ch & 1)) PFga16[(size_t)v * 16 + (ch >> 1)] = packbf2(pf, hi);
}

// ===========================================================================
// ga edge kernel: one wave (64 lanes) per cut node, lane = edge-slot.
// slot = {tgt, eid}; gather ea via eid; gather bf16 PFga row via tgt.
// ===========================================================================
__global__ __launch_bounds__(256) void ga_edge_kernel(
    const float* __restrict__ PXga, const unsigned* __restrict__ PFga16,
    const int2* __restrict__ slot_a, const float* __restrict__ ea_a,
    const int* __restrict__ off_a, const int* __restrict__ deg_a,
    const float* __restrict__ gaW1,
    float* __restrict__ Aga, int nA)
{
    int gid = blockIdx.x * 256 + threadIdx.x;
    int a   = gid >> 6;
    int ln  = threadIdx.x & 63;
    if (a >= nA) return;

    float px[HD], acc[HD];
    {
        const float4* pp = reinterpret_cast<const float4*>(PXga + (size_t)a * HD);
#pragma unroll
        for (int q = 0; q < 8; q++) {
            float4 t = pp[q];
            px[4*q+0] = t.x; px[4*q+1] = t.y; px[4*q+2] = t.z; px[4*q+3] = t.w;
        }
    }
#pragma unroll
    for (int ch = 0; ch < HD; ch++) acc[ch] = 0.f;

    int base = off_a[a], d = deg_a[a];
    for (int k = ln; k < d; k += 64) {
        int2 w = slot_a[base + k];
        int t = w.x, e = w.y;
        const uint4* pr = reinterpret_cast<const uint4*>(PFga16 + (size_t)t * 16);
        uint4 r0 = pr[0], r1 = pr[1], r2 = pr[2], r3 = pr[3];
        const float4* pe = reinterpret_cast<const float4*>(ea_a + (size_t)e * ED);
        float4 q0 = pe[0], q1 = pe[1];
        float pf[HD], ev[ED];
        unpack8(r0, pf + 0); unpack8(r1, pf + 8);
        unpack8(r2, pf + 16); unpack8(r3, pf + 24);
        ev[0]=q0.x; ev[1]=q0.y; ev[2]=q0.z; ev[3]=q0.w;
        ev[4]=q1.x; ev[5]=q1.y; ev[6]=q1.z; ev[7]=q1.w;
#pragma unroll
        for (int ch = 0; ch < HD; ch++) {
            float t2 = px[ch] + pf[ch];
#pragma unroll
            for (int i = 0; i < ED; i++) t2 = fmaf(ev[i], gaW1[(ND + HD + i) * HD + ch], t2);
            acc[ch] += fmaxf(t2, 0.f);
        }
    }
#pragma unroll
    for (int m = 1; m < 64; m <<= 1) {
#pragma unroll
        for (int ch = 0; ch < HD; ch++) acc[ch] += __shfl_xor(acc[ch], m, 64);
    }
    if (ln == 0) {
        float4* dst = reinterpret_cast<float4*>(Aga + (size_t)a * HD);
#pragma unroll
        for (int q = 0; q < 8; q++)
            dst[q] = make_float4(acc[4*q+0], acc[4*q+1], acc[4*q+2], acc[4*q+3]);
    }
}

// ===========================================================================
// fa node kernel, CHANNEL-PARALLEL: thread = (a, ch) -> final output.
// ===========================================================================
__global__ __launch_bounds__(256) void fa_node_kernel(
    const float* __restrict__ xa,
    const float* __restrict__ Aga, const int* __restrict__ deg_a,
    const float* __restrict__ faW1, const float* __restrict__ fab1,
    const float* __restrict__ faW2, const float* __restrict__ fab2,
    const float* __restrict__ Mga, const float* __restrict__ bga,
    float* __restrict__ out, int nA)
{
    __shared__ float sM[1024], sW2[1024], sF[512];
    __shared__ float sbga[32], sb1[32], sb2[32];
    for (int i = threadIdx.x; i < 1024; i += 256) { sM[i] = Mga[i]; sW2[i] = faW2[i]; }
    for (int i = threadIdx.x; i < 512; i += 256) sF[i] = faW1[i];
    if (threadIdx.x < 32) {
        sbga[threadIdx.x] = bga[threadIdx.x];
        sb1[threadIdx.x]  = fab1[threadIdx.x];
        sb2[threadIdx.x]  = fab2[threadIdx.x];
    }
    __syncthreads();

    int gid = blockIdx.x * 256 + threadIdx.x;
    int a = gid >> 5, ch = threadIdx.x & 31;
    if (a >= nA) return;

    float x = (ch < ND) ? xa[(size_t)a * ND + ch] : 0.f;
    float t = sb1[ch];
#pragma unroll
    for (int i = 0; i < ND; i++) t = fmaf(__shfl(x, i, 32), sF[i * 32 + ch], t);

    float agr[HD];
    {
        const float4* pg4 = reinterpret_cast<const float4*>(Aga + (size_t)a * HD);
#pragma unroll
        for (int q = 0; q < 8; q++) {
            float4 w = pg4[q];
            agr[4*q+0] = w.x; agr[4*q+1] = w.y; agr[4*q+2] = w.z; agr[4*q+3] = w.w;
        }
    }
    float s = 0.f;
#pragma unroll
    for (int c = 0; c < HD; c++) s = fmaf(agr[c], sM[c * 32 + ch], s);
    int d = deg_a[a];
    float inv = d > 0 ? 1.f / (float)d : 0.f;
    t += (d > 0 ? sbga[ch] : 0.f) + inv * s;
    float hid = fmaxf(t, 0.f);

    float o = sb2[ch];
#pragma unroll
    for (int h = 0; h < HD; h++) o = fmaf(__shfl(hid, h, 32), sW2[h * 32 + ch], o);
    out[(size_t)a * HD + ch] = o;
}

// ===========================================================================
extern "C" void kernel_launch(void* const* d_in, const int* in_sizes, int n_in,
                              void* d_out, int out_size, void* d_ws, size_t ws_size,
                              hipStream_t stream) {
    const float* x_c    = (const float*)d_in[0];
    const float* x_v    = (const float*)d_in[1];
    const float* x_a    = (const float*)d_in[2];
    const int*   ei_c2v = (const int*)d_in[3];
    const int*   ei_a2v = (const int*)d_in[4];
    const float* ea_c2v = (const float*)d_in[5];
    const float* ea_a2v = (const float*)d_in[6];
    const float *gv_W1=(const float*)d_in[7],  *gv_b1=(const float*)d_in[8],
                *gv_W2=(const float*)d_in[9],  *gv_b2=(const float*)d_in[10];
    const float *hv_W1=(const float*)d_in[11], *hv_b1=(const float*)d_in[12],
                *hv_W2=(const float*)d_in[13], *hv_b2=(const float*)d_in[14];
    const float *fv_W1=(const float*)d_in[15], *fv_b1=(const float*)d_in[16],
                *fv_W2=(const float*)d_in[17], *fv_b2=(const float*)d_in[18];
    const float *ga_W1=(const float*)d_in[19], *ga_b1=(const float*)d_in[20],
                *ga_W2=(const float*)d_in[21], *ga_b2=(const float*)d_in[22];
    const float *fa_W1=(const float*)d_in[23], *fa_b1=(const float*)d_in[24],
                *fa_W2=(const float*)d_in[25], *fa_b2=(const float*)d_in[26];

    const int NC = in_sizes[0] / ND;
    const int NV = in_sizes[1] / ND;
    const int NA = in_sizes[2] / ND;
    const int EC = in_sizes[3] / 2;
    const int EA = in_sizes[4] / 2;
    (void)n_in; (void)out_size; (void)ws_size;

    const int* c2v_s = ei_c2v;            // constraint side of c2v
    const int* c2v_t = ei_c2v + EC;       // variable side
    const int* a2v_s = ei_a2v;            // cut node side
    const int* a2v_t = ei_a2v + EA;       // variable side

    const int chunksV = (NV + 1023) / 1024;
    const int chunksA = (NA + 1023) / 1024;
    const int csizeV = (NV + NPART - 1) / NPART;   // must be <= MAXCSV
    const int csizeA = (NA + NPART - 1) / NPART;   // must be <= MAXCSA

    // Workspace layout (4B words)
    int* wsI = (int*)d_ws;
    int* deg_g = wsI;                 // NV
    int* deg_h = deg_g + NV;          // NV
    int* deg_a = deg_h + NV;          // NA
    int* off_g = deg_a + NA;          // NV
    int* off_h = off_g + NV;          // NV
    int* off_a = off_h + NV;          // NA
    int* csum_g = off_a + NA;         // 1024
    int* csum_h = csum_g + 1024;      // 1024
    int* csum_a = csum_h + 1024;      // 1024
    int* cnt_g = csum_a + 1024;                       // NPART*NCH*csizeV
    int* cnt_h = cnt_g + (size_t)NPART * NCH * csizeV; // NPART*NCH*csizeV
    int* cnt_a = cnt_h + (size_t)NPART * NCH * csizeV; // NPART*NCH*csizeA
    int* endcnt = cnt_a + (size_t)NPART * NCH * csizeA;
    size_t words = (size_t)(endcnt - wsI);
    if (words & 1) words++;                            // 8B-align slots
    int2* slot_g = (int2*)(wsI + words);    // EC
    int2* slot_h = slot_g + EC;             // EA
    int2* slot_a = slot_h + EA;             // EA
    float* PXg = (float*)(slot_a + EA);     // NV*32 (aliased as PFga16 later)
    float* PXh = PXg + (size_t)NV * HD;     // NV*32
    float* PXga= PXh + (size_t)NV * HD;     // NA*32
    float* Ag  = PXga + (size_t)NA * HD;    // NV*32
    float* Ah  = Ag + (size_t)NV * HD;      // NV*32
    float* Aga = Ah + (size_t)NV * HD;      // NA*32
    unsigned* PCg16 = (unsigned*)(Aga + (size_t)NA * HD);  // NC*16
    unsigned* PAh16 = PCg16 + (size_t)NC * 16;             // NA*16
    float* Mg  = (float*)(PAh16 + (size_t)NA * 16);        // 1024
    float* Mh  = Mg + HD * HD;            // 1024
    float* Mga = Mh + HD * HD;            // 1024
    float* Nfv = Mga + HD * HD;           // 1024
    float* bgv = Nfv + HD * HD;           // 32
    float* bhv = bgv + HD;                // 32
    float* bgav= bhv + HD;                // 32
    float* bfv = bgav + HD;               // 32
    unsigned* PFga16 = (unsigned*)PXg;    // alias: PXg dead after fv_edge

    // standalone precompute (independent of CSR build)
    {
        int bV = (NV * 32 + 255) / 256, bC = (NC * 32 + 255) / 256, bA = (NA * 32 + 255) / 256;
        precompC_kernel<<<bV + bC + bA + 4, 256, 0, stream>>>(
            x_v, x_c, x_a,
            gv_W1, gv_b1, hv_W1, hv_b1, ga_W1, ga_b1,
            gv_W2, gv_b2, hv_W2, hv_b2, ga_W2, ga_b2,
            fv_W1, fv_W2, fv_b2, fa_W1,
            PXg, PXh, PXga, PCg16, PAh16,
            Mg, bgv, Mh, bhv, Mga, bgav, Nfv, bfv, NV, NC, NA);
    }

    // pass A: atomic-free LDS histograms -> per-(part,chunk) counts
    countP_kernel<<<2 * NPART * NCH, 256, 0, stream>>>(
        c2v_t, cnt_g, EC, a2v_t, a2v_s, cnt_h, cnt_a, EA, csizeV, csizeA);

    // deg = sum over chunks
    int degThreads = 2 * NV + NA;
    degsum_kernel<<<(degThreads + 255) / 256, 256, 0, stream>>>(
        cnt_g, cnt_h, cnt_a, deg_g, deg_h, deg_a, NV, NA, csizeV, csizeA);

    // global exclusive scans -> off
    scan_p1f<<<2 * chunksV + chunksA, 256, 0, stream>>>(
        deg_g, deg_h, deg_a, csum_g, csum_h, csum_a, NV, NA, chunksV);
    scan_p2<<<3, 1024, 0, stream>>>(csum_g, chunksV, csum_h, chunksV, csum_a, chunksA);
    scan_p3f<<<2 * chunksV + chunksA, 1024, 0, stream>>>(
        deg_g, deg_h, deg_a, csum_g, csum_h, csum_a,
        off_g, off_h, off_a, NV, NA, chunksV);

    // per-(chunk,node) write bases (in place over cnt arrays)
    chunkbase_kernel<<<(degThreads + 255) / 256, 256, 0, stream>>>(
        cnt_g, cnt_h, cnt_a, off_g, off_h, off_a, NV, NA, csizeV, csizeA);

    // pass B: atomic-free scatter (LDS slot assignment, XCD-local writes)
    scatterB_kernel<<<2 * NPART * NCH, 256, 0, stream>>>(
        c2v_t, c2v_s, cnt_g, slot_g, EC,
        a2v_t, a2v_s, cnt_h, cnt_a, slot_h, slot_a, EA, csizeV, csizeA);

    // variable-node edge aggregation (8 lanes/node)
    fv_edge_kernel<<<(NV * 8 + 255) / 256, 256, 0, stream>>>(
        PXg, PCg16, PXh, PAh16, slot_g, slot_h, ea_c2v, ea_a2v,
        off_g, deg_g, off_h, deg_h, gv_W1, hv_W1, Ag, Ah, NV);

    // variable-node MLP -> PFga16 (channel-parallel; f_v folded into ga partial)
    fv_node_kernel<<<(NV * 32 + 255) / 256, 256, 0, stream>>>(
        x_v, Ag, Ah, deg_g, deg_h,
        fv_W1, fv_b1, Mg, bgv, Mh, bhv, Nfv, bfv, PFga16, NV);

    // cut-node edge aggregation (64 lanes/node)
    ga_edge_kernel<<<(NA * 64 + 255) / 256, 256, 0, stream>>>(
        PXga, PFga16, slot_a, ea_a2v,
        off_a, deg_a, ga_W1, Aga, NA);

    // cut-node MLP -> output (channel-parallel)
    fa_node_kernel<<<(NA * 32 + 255) / 256, 256, 0, stream>>>(
        x_a, Aga, deg_a,
        fa_W1, fa_b1, fa_W2, fa_b2, Mga, bgav, (float*)d_out, NA);
}

// Round 11
// 421.970 us; speedup vs baseline: 1.4145x; 1.4145x over previous
//
#include <hip/hip_runtime.h>

#define HD 32    // hidden/emb dim
#define ND 16    // node feature dim
#define ED 8     // edge feature dim
#define NPART 8  // one partition per XCD (blockIdx & 7 -> XCD round-robin)
#define MAXCSV 12544  // max ceil(NV/NPART) supported by LDS histogram
#define MAXCSA 640    // max ceil(NA/NPART)

// ---------------- bf16 pack/unpack helpers ----------------
__device__ __forceinline__ unsigned bf16rne(float f) {
    unsigned u = __float_as_uint(f);
    return (u + 0x7fffu + ((u >> 16) & 1u)) >> 16;
}
__device__ __forceinline__ unsigned packbf2(float lo, float hi) {
    return bf16rne(lo) | (bf16rne(hi) << 16);
}
__device__ __forceinline__ void unpack8(uint4 r, float* p) {
    p[0] = __uint_as_float(r.x << 16); p[1] = __uint_as_float(r.x & 0xffff0000u);
    p[2] = __uint_as_float(r.y << 16); p[3] = __uint_as_float(r.y & 0xffff0000u);
    p[4] = __uint_as_float(r.z << 16); p[5] = __uint_as_float(r.z & 0xffff0000u);
    p[6] = __uint_as_float(r.w << 16); p[7] = __uint_as_float(r.w & 0xffff0000u);
}

// ===========================================================================
// Standalone channel-parallel precompute (no dependence on CSR).
// ===========================================================================
__global__ __launch_bounds__(256) void precompC_kernel(
    const float* __restrict__ xv, const float* __restrict__ xc, const float* __restrict__ xa,
    const float* __restrict__ gvW1, const float* __restrict__ gvb1,
    const float* __restrict__ hvW1, const float* __restrict__ hvb1,
    const float* __restrict__ gaW1, const float* __restrict__ gab1,
    const float* __restrict__ gvW2, const float* __restrict__ gvb2,
    const float* __restrict__ hvW2, const float* __restrict__ hvb2,
    const float* __restrict__ gaW2, const float* __restrict__ gab2,
    const float* __restrict__ fvW1, const float* __restrict__ fvW2,
    const float* __restrict__ fvb2, const float* __restrict__ faW1,
    float* __restrict__ PXg, float* __restrict__ PXh, float* __restrict__ PXga,
    unsigned* __restrict__ PCg16, unsigned* __restrict__ PAh16,
    float* __restrict__ Mg, float* __restrict__ bg,
    float* __restrict__ Mh, float* __restrict__ bh,
    float* __restrict__ Mga, float* __restrict__ bga,
    float* __restrict__ Nfv, float* __restrict__ bfv,
    int nV, int nC, int nA)
{
    int bV = (nV * 32 + 255) / 256, bC = (nC * 32 + 255) / 256, bA = (nA * 32 + 255) / 256;
    int b = blockIdx.x;
    int tid = threadIdx.x;
    int ch = tid & 31;
    __shared__ float s0[512], s1[512];

    if (b < bV) {                        // ---- PXg, PXh (f32) ----
        for (int i = tid; i < 512; i += 256) { s0[i] = gvW1[i]; s1[i] = hvW1[i]; }
        __syncthreads();
        int v = (b * 256 + tid) >> 5;
        if (v >= nV) return;
        float x = (ch < ND) ? xv[(size_t)v * ND + ch] : 0.f;
        float pg = gvb1[ch], ph = hvb1[ch];
#pragma unroll
        for (int i = 0; i < ND; i++) {
            float xi = __shfl(x, i, 32);
            pg = fmaf(xi, s0[i * 32 + ch], pg);
            ph = fmaf(xi, s1[i * 32 + ch], ph);
        }
        PXg[(size_t)v * 32 + ch] = pg;
        PXh[(size_t)v * 32 + ch] = ph;
    } else if (b < bV + bC) {            // ---- PCg16 (bf16) ----
        for (int i = tid; i < 512; i += 256) s0[i] = gvW1[512 + i];
        __syncthreads();
        int c = ((b - bV) * 256 + tid) >> 5;
        if (c >= nC) return;
        float x = (ch < ND) ? xc[(size_t)c * ND + ch] : 0.f;
        float p = 0.f;
#pragma unroll
        for (int i = 0; i < ND; i++) p = fmaf(__shfl(x, i, 32), s0[i * 32 + ch], p);
        float hi = __shfl_xor(p, 1, 32);
        if (!(ch & 1)) PCg16[(size_t)c * 16 + (ch >> 1)] = packbf2(p, hi);
    } else if (b < bV + bC + bA) {       // ---- PAh16 (bf16), PXga (f32) ----
        for (int i = tid; i < 512; i += 256) { s0[i] = hvW1[512 + i]; s1[i] = gaW1[i]; }
        __syncthreads();
        int a = ((b - bV - bC) * 256 + tid) >> 5;
        if (a >= nA) return;
        float x = (ch < ND) ? xa[(size_t)a * ND + ch] : 0.f;
        float ph = 0.f, pg = gab1[ch];
#pragma unroll
        for (int i = 0; i < ND; i++) {
            float xi = __shfl(x, i, 32);
            ph = fmaf(xi, s0[i * 32 + ch], ph);
            pg = fmaf(xi, s1[i * 32 + ch], pg);
        }
        float hi = __shfl_xor(ph, 1, 32);
        if (!(ch & 1)) PAh16[(size_t)a * 16 + (ch >> 1)] = packbf2(ph, hi);
        PXga[(size_t)a * 32 + ch] = pg;
    } else {                             // ---- folded layer-2 matrices ----
        int m = b - (bV + bC + bA);
        const float *W2, *b2, *T; float *M, *bb; int toff;
        if (m == 0)      { W2 = gvW2; b2 = gvb2; T = fvW1; toff = ND;      M = Mg;  bb = bg;  }
        else if (m == 1) { W2 = hvW2; b2 = hvb2; T = fvW1; toff = ND + HD; M = Mh;  bb = bh;  }
        else if (m == 2) { W2 = gaW2; b2 = gab2; T = faW1; toff = ND;      M = Mga; bb = bga; }
        else             { W2 = fvW2; b2 = fvb2; T = gaW1; toff = ND;      M = Nfv; bb = bfv; }
        for (int idx = tid; idx < 1024; idx += 256) {
            int c = idx >> 5, h = idx & 31;
            float s = 0.f;
#pragma unroll
            for (int o = 0; o < HD; o++) s = fmaf(W2[c * HD + o], T[(toff + o) * HD + h], s);
            M[idx] = s;
        }
        if (tid < HD) {
            int h = tid;
            float s = 0.f;
#pragma unroll
            for (int o = 0; o < HD; o++) s = fmaf(b2[o], T[(toff + o) * HD + h], s);
            bb[h] = s;
        }
    }
}

// ===========================================================================
// Pass A: atomic-free per-(partition,chunk) LDS histogram.
// grid = 2*NPART*nch: part = bid&7, r = bid>>3, chunk = r%nch, list = r/nch.
// ===========================================================================
__global__ __launch_bounds__(256) void countP_kernel(
    const int* __restrict__ c2v_t, int* __restrict__ cnt_g, int nEC,
    const int* __restrict__ a2v_t, const int* __restrict__ a2v_s,
    int* __restrict__ cnt_h, int* __restrict__ cnt_a, int nEA,
    int csizeV, int csizeA, int nch)
{
    __shared__ int lcnt[MAXCSV + MAXCSA];
    int b = blockIdx.x;
    int part  = b & (NPART - 1);
    int r     = b >> 3;
    int chunk = r % nch;
    int list  = r / nch;
    int tid = threadIdx.x;
    int loV = part * csizeV, loA = part * csizeA;

    if (list == 0) {
        for (int i = tid; i < csizeV; i += 256) lcnt[i] = 0;
        __syncthreads();
        int CH = ((nEC + nch - 1) / nch + 255) & ~255;
        int i0 = chunk * CH, i1 = min(i0 + CH, nEC);
        for (int i = i0 + tid; i < i1; i += 256) {
            int t = c2v_t[i];
            if ((unsigned)(t - loV) < (unsigned)csizeV) atomicAdd(&lcnt[t - loV], 1);
        }
        __syncthreads();
        int* out = cnt_g + (size_t)(part * nch + chunk) * csizeV;
        for (int i = tid; i < csizeV; i += 256) out[i] = lcnt[i];
    } else {
        for (int i = tid; i < csizeV + csizeA; i += 256) lcnt[i] = 0;
        __syncthreads();
        int CH = ((nEA + nch - 1) / nch + 255) & ~255;
        int i0 = chunk * CH, i1 = min(i0 + CH, nEA);
        for (int i = i0 + tid; i < i1; i += 256) {
            int t = a2v_t[i];
            int s = a2v_s[i];
            if ((unsigned)(t - loV) < (unsigned)csizeV) atomicAdd(&lcnt[t - loV], 1);
            if ((unsigned)(s - loA) < (unsigned)csizeA) atomicAdd(&lcnt[csizeV + s - loA], 1);
        }
        __syncthreads();
        int* outh = cnt_h + (size_t)(part * nch + chunk) * csizeV;
        for (int i = tid; i < csizeV; i += 256) outh[i] = lcnt[i];
        int* outa = cnt_a + (size_t)(part * nch + chunk) * csizeA;
        for (int i = tid; i < csizeA; i += 256) outa[i] = lcnt[csizeV + i];
    }
}

// deg[v] = sum over chunks of cnt[(p*nch+c)*csize + idx]
__global__ __launch_bounds__(256) void degsum_kernel(
    const int* __restrict__ cnt_g, const int* __restrict__ cnt_h,
    const int* __restrict__ cnt_a,
    int* __restrict__ deg_g, int* __restrict__ deg_h, int* __restrict__ deg_a,
    int nV, int nA, int csizeV, int csizeA, int nch)
{
    int i = blockIdx.x * 256 + threadIdx.x;
    const int* cnt; int* deg; int csize, idx0;
    if (i < nV)                { cnt = cnt_g; deg = deg_g; csize = csizeV; idx0 = i; }
    else if (i < 2 * nV)       { cnt = cnt_h; deg = deg_h; csize = csizeV; idx0 = i - nV; }
    else if (i < 2 * nV + nA)  { cnt = cnt_a; deg = deg_a; csize = csizeA; idx0 = i - 2 * nV; }
    else return;
    int p = idx0 / csize, idx = idx0 - p * csize;
    const int* base = cnt + (size_t)(p * nch) * csize + idx;
    int s = 0;
    for (int c = 0; c < nch; c++) s += base[(size_t)c * csize];
    deg[idx0] = s;
}

// in-place: cnt[(p*nch+c)*csize + idx] <- off[v] + prefix over chunks
__global__ __launch_bounds__(256) void chunkbase_kernel(
    int* __restrict__ cnt_g, int* __restrict__ cnt_h, int* __restrict__ cnt_a,
    const int* __restrict__ off_g, const int* __restrict__ off_h,
    const int* __restrict__ off_a,
    int nV, int nA, int csizeV, int csizeA, int nch)
{
    int i = blockIdx.x * 256 + threadIdx.x;
    int* cnt; const int* off; int csize, idx0;
    if (i < nV)                { cnt = cnt_g; off = off_g; csize = csizeV; idx0 = i; }
    else if (i < 2 * nV)       { cnt = cnt_h; off = off_h; csize = csizeV; idx0 = i - nV; }
    else if (i < 2 * nV + nA)  { cnt = cnt_a; off = off_a; csize = csizeA; idx0 = i - 2 * nV; }
    else return;
    int p = idx0 / csize, idx = idx0 - p * csize;
    int* base = cnt + (size_t)(p * nch) * csize + idx;
    int running = off[idx0];
    for (int c = 0; c < nch; c++) {
        int t = base[(size_t)c * csize];
        base[(size_t)c * csize] = running;
        running += t;
    }
}

// pass 1 (fused over 3 arrays): per-1024-chunk sums
__global__ __launch_bounds__(256) void scan_p1f(
    const int* __restrict__ dg, const int* __restrict__ dh, const int* __restrict__ da,
    int* __restrict__ cg, int* __restrict__ chs, int* __restrict__ ca,
    int nV, int nA, int chunksV)
{
    int b = blockIdx.x;
    const int* in; int* cs; int n; int c;
    if (b < chunksV)            { in = dg; cs = cg;  n = nV; c = b; }
    else if (b < 2 * chunksV)   { in = dh; cs = chs; n = nV; c = b - chunksV; }
    else                        { in = da; cs = ca;  n = nA; c = b - 2 * chunksV; }

    int i0 = c * 1024 + threadIdx.x * 4;
    int s = 0;
#pragma unroll
    for (int j = 0; j < 4; j++) { int i = i0 + j; if (i < n) s += in[i]; }
#pragma unroll
    for (int m = 1; m < 64; m <<= 1) s += __shfl_xor(s, m, 64);
    __shared__ int ws[4];
    if ((threadIdx.x & 63) == 0) ws[threadIdx.x >> 6] = s;
    __syncthreads();
    if (threadIdx.x == 0) cs[c] = ws[0] + ws[1] + ws[2] + ws[3];
}

__device__ __forceinline__ void exscan_block(int* __restrict__ c, int n)
{
    int i = threadIdx.x;
    int v = (i < n) ? c[i] : 0;
    int x = v;
    int lane = i & 63, wid = i >> 6;
#pragma unroll
    for (int dd = 1; dd < 64; dd <<= 1) {
        int y = __shfl_up(x, dd, 64);
        if (lane >= dd) x += y;
    }
    __shared__ int ws[16];
    if (lane == 63) ws[wid] = x;
    __syncthreads();
    if (i == 0) {
        int a = 0;
#pragma unroll
        for (int w = 0; w < 16; w++) { int t = ws[w]; ws[w] = a; a += t; }
    }
    __syncthreads();
    int excl = ws[wid] + x - v;
    if (i < n) c[i] = excl;
}

__global__ __launch_bounds__(1024) void scan_p2(
    int* c0, int n0, int* c1, int n1, int* c2, int n2)
{
    if (blockIdx.x == 0)      exscan_block(c0, n0);
    else if (blockIdx.x == 1) exscan_block(c1, n1);
    else                      exscan_block(c2, n2);
}

__global__ __launch_bounds__(1024) void scan_p3f(
    const int* __restrict__ dg, const int* __restrict__ dh, const int* __restrict__ da,
    const int* __restrict__ cg, const int* __restrict__ chs, const int* __restrict__ ca,
    int* __restrict__ og, int* __restrict__ oh, int* __restrict__ oa,
    int nV, int nA, int chunksV)
{
    int b = blockIdx.x;
    const int* deg; const int* cbase; int* off; int n; int c;
    if (b < chunksV)          { deg = dg; cbase = cg;  off = og; n = nV; c = b; }
    else if (b < 2 * chunksV) { deg = dh; cbase = chs; off = oh; n = nV; c = b - chunksV; }
    else                      { deg = da; cbase = ca;  off = oa; n = nA; c = b - 2 * chunksV; }

    int i = c * 1024 + threadIdx.x;
    int v = (i < n) ? deg[i] : 0;
    int x = v;
    int lane = threadIdx.x & 63, wid = threadIdx.x >> 6;
#pragma unroll
    for (int dd = 1; dd < 64; dd <<= 1) {
        int y = __shfl_up(x, dd, 64);
        if (lane >= dd) x += y;
    }
    __shared__ int ws[16];
    if (lane == 63) ws[wid] = x;
    __syncthreads();
    if (threadIdx.x == 0) {
        int a = 0;
#pragma unroll
        for (int w = 0; w < 16; w++) { int t = ws[w]; ws[w] = a; a += t; }
    }
    __syncthreads();
    int excl = cbase[c] + ws[wid] + x - v;
    if (i < n) off[i] = excl;
}

// ===========================================================================
// Pass B: atomic-free scatter. Same (list, part, chunk) decomposition as
// pass A; per-block write bases loaded into LDS, slots assigned via LDS
// atomics, slot stores contiguous per partition (XCD-local). No global
// atomics anywhere.
// ===========================================================================
__global__ __launch_bounds__(256) void scatterB_kernel(
    const int* __restrict__ c2v_t, const int* __restrict__ c2v_s,
    const int* __restrict__ cnt_g, int2* __restrict__ slot_g, int nEC,
    const int* __restrict__ a2v_t, const int* __restrict__ a2v_s,
    const int* __restrict__ cnt_h, const int* __restrict__ cnt_a,
    int2* __restrict__ slot_h, int2* __restrict__ slot_a, int nEA,
    int csizeV, int csizeA, int nch)
{
    __shared__ int lbase[MAXCSV + MAXCSA];
    int b = blockIdx.x;
    int part  = b & (NPART - 1);
    int r     = b >> 3;
    int chunk = r % nch;
    int list  = r / nch;
    int tid = threadIdx.x;
    int loV = part * csizeV, loA = part * csizeA;

    if (list == 0) {
        const int* src = cnt_g + (size_t)(part * nch + chunk) * csizeV;
        for (int i = tid; i < csizeV; i += 256) lbase[i] = src[i];
        __syncthreads();
        int CH = ((nEC + nch - 1) / nch + 255) & ~255;
        int i0 = chunk * CH, i1 = min(i0 + CH, nEC);
        for (int i = i0 + tid; i < i1; i += 256) {
            int t = c2v_t[i];
            if ((unsigned)(t - loV) < (unsigned)csizeV) {
                int p = atomicAdd(&lbase[t - loV], 1);
                slot_g[p] = make_int2(c2v_s[i], i);
            }
        }
    } else {
        const int* srch = cnt_h + (size_t)(part * nch + chunk) * csizeV;
        for (int i = tid; i < csizeV; i += 256) lbase[i] = srch[i];
        const int* srca = cnt_a + (size_t)(part * nch + chunk) * csizeA;
        for (int i = tid; i < csizeA; i += 256) lbase[csizeV + i] = srca[i];
        __syncthreads();
        int CH = ((nEA + nch - 1) / nch + 255) & ~255;
        int i0 = chunk * CH, i1 = min(i0 + CH, nEA);
        for (int i = i0 + tid; i < i1; i += 256) {
            int t = a2v_t[i];
            int s = a2v_s[i];
            if ((unsigned)(t - loV) < (unsigned)csizeV) {
                int p = atomicAdd(&lbase[t - loV], 1);
                slot_h[p] = make_int2(s, i);
            }
            if ((unsigned)(s - loA) < (unsigned)csizeA) {
                int q = atomicAdd(&lbase[csizeV + s - loA], 1);
                slot_a[q] = make_int2(t, i);
            }
        }
    }
}

// ===========================================================================
// fv edge kernel: 8 lanes per variable node, lane = edge-slot.
// ===========================================================================
__global__ __launch_bounds__(256) void fv_edge_kernel(
    const float* __restrict__ PXg, const unsigned* __restrict__ PCg16,
    const float* __restrict__ PXh, const unsigned* __restrict__ PAh16,
    const int2* __restrict__ slot_g, const int2* __restrict__ slot_h,
    const float* __restrict__ ea_c, const float* __restrict__ ea_a,
    const int* __restrict__ off_g, const int* __restrict__ deg_g,
    const int* __restrict__ off_h, const int* __restrict__ deg_h,
    const float* __restrict__ gvW1, const float* __restrict__ hvW1,
    float* __restrict__ Ag, float* __restrict__ Ah, int nV)
{
    int gid = blockIdx.x * 256 + threadIdx.x;
    int v   = gid >> 3;
    int sub = threadIdx.x & 7;
    if (v >= nV) return;

    float px[HD], acc[HD];

    // ---------------- g: c2v edges ----------------
    {
        const float4* pp = reinterpret_cast<const float4*>(PXg + (size_t)v * HD);
#pragma unroll
        for (int q = 0; q < 8; q++) {
            float4 t = pp[q];
            px[4*q+0] = t.x; px[4*q+1] = t.y; px[4*q+2] = t.z; px[4*q+3] = t.w;
        }
#pragma unroll
        for (int ch = 0; ch < HD; ch++) acc[ch] = 0.f;

        int base = off_g[v], d = deg_g[v];
        for (int k = sub; k < d; k += 8) {
            int2 w = slot_g[base + k];
            int s = w.x, e = w.y;
            const uint4* pr = reinterpret_cast<const uint4*>(PCg16 + (size_t)s * 16);
            uint4 r0 = pr[0], r1 = pr[1], r2 = pr[2], r3 = pr[3];
            const float4* pe = reinterpret_cast<const float4*>(ea_c + (size_t)e * ED);
            float4 q0 = pe[0], q1 = pe[1];
            float pc[HD], ev[ED];
            unpack8(r0, pc + 0); unpack8(r1, pc + 8);
            unpack8(r2, pc + 16); unpack8(r3, pc + 24);
            ev[0]=q0.x; ev[1]=q0.y; ev[2]=q0.z; ev[3]=q0.w;
            ev[4]=q1.x; ev[5]=q1.y; ev[6]=q1.z; ev[7]=q1.w;
#pragma unroll
            for (int ch = 0; ch < HD; ch++) {
                float t = px[ch] + pc[ch];
#pragma unroll
                for (int i = 0; i < ED; i++) t = fmaf(ev[i], gvW1[(2 * ND + i) * HD + ch], t);
                acc[ch] += fmaxf(t, 0.f);
            }
        }
#pragma unroll
        for (int m = 1; m < 8; m <<= 1) {
#pragma unroll
            for (int ch = 0; ch < HD; ch++) acc[ch] += __shfl_xor(acc[ch], m, 64);
        }
        if (sub == 0) {
            float4* dst = reinterpret_cast<float4*>(Ag + (size_t)v * HD);
#pragma unroll
            for (int q = 0; q < 8; q++)
                dst[q] = make_float4(acc[4*q+0], acc[4*q+1], acc[4*q+2], acc[4*q+3]);
        }
    }

    // ---------------- h: a2v edges ----------------
    {
        const float4* pp = reinterpret_cast<const float4*>(PXh + (size_t)v * HD);
#pragma unroll
        for (int q = 0; q < 8; q++) {
            float4 t = pp[q];
            px[4*q+0] = t.x; px[4*q+1] = t.y; px[4*q+2] = t.z; px[4*q+3] = t.w;
        }
#pragma unroll
        for (int ch = 0; ch < HD; ch++) acc[ch] = 0.f;

        int base = off_h[v], d = deg_h[v];
        for (int k = sub; k < d; k += 8) {
            int2 w = slot_h[base + k];
            int s = w.x, e = w.y;
            const uint4* pr = reinterpret_cast<const uint4*>(PAh16 + (size_t)s * 16);
            uint4 r0 = pr[0], r1 = pr[1], r2 = pr[2], r3 = pr[3];
            const float4* pe = reinterpret_cast<const float4*>(ea_a + (size_t)e * ED);
            float4 q0 = pe[0], q1 = pe[1];
            float pc[HD], ev[ED];
            unpack8(r0, pc + 0); unpack8(r1, pc + 8);
            unpack8(r2, pc + 16); unpack8(r3, pc + 24);
            ev[0]=q0.x; ev[1]=q0.y; ev[2]=q0.z; ev[3]=q0.w;
            ev[4]=q1.x; ev[5]=q1.y; ev[6]=q1.z; ev[7]=q1.w;
#pragma unroll
            for (int ch = 0; ch < HD; ch++) {
                float t = px[ch] + pc[ch];
#pragma unroll
                for (int i = 0; i < ED; i++) t = fmaf(ev[i], hvW1[(2 * ND + i) * HD + ch], t);
                acc[ch] += fmaxf(t, 0.f);
            }
        }
#pragma unroll
        for (int m = 1; m < 8; m <<= 1) {
#pragma unroll
            for (int ch = 0; ch < HD; ch++) acc[ch] += __shfl_xor(acc[ch], m, 64);
        }
        if (sub == 0) {
            float4* dst = reinterpret_cast<float4*>(Ah + (size_t)v * HD);
#pragma unroll
            for (int q = 0; q < 8; q++)
                dst[q] = make_float4(acc[4*q+0], acc[4*q+1], acc[4*q+2], acc[4*q+3]);
        }
    }
}

// ===========================================================================
// fv node kernel, CHANNEL-PARALLEL: thread = (v, ch).
// ===========================================================================
__global__ __launch_bounds__(256) void fv_node_kernel(
    const float* __restrict__ xv,
    const float* __restrict__ Ag, const float* __restrict__ Ah,
    const int* __restrict__ deg_g, const int* __restrict__ deg_h,
    const float* __restrict__ fvW1, const float* __restrict__ fvb1,
    const float* __restrict__ Mg, const float* __restrict__ bg,
    const float* __restrict__ Mh, const float* __restrict__ bh,
    const float* __restrict__ Nfv, const float* __restrict__ bfv,
    unsigned* __restrict__ PFga16, int nV)
{
    __shared__ float sMg[1024], sMh[1024], sN[1024], sF[512];
    __shared__ float sbg[32], sbh[32], sbf[32], sb1[32];
    for (int i = threadIdx.x; i < 1024; i += 256) {
        sMg[i] = Mg[i]; sMh[i] = Mh[i]; sN[i] = Nfv[i];
    }
    for (int i = threadIdx.x; i < 512; i += 256) sF[i] = fvW1[i];
    if (threadIdx.x < 32) {
        sbg[threadIdx.x] = bg[threadIdx.x];
        sbh[threadIdx.x] = bh[threadIdx.x];
        sbf[threadIdx.x] = bfv[threadIdx.x];
        sb1[threadIdx.x] = fvb1[threadIdx.x];
    }
    __syncthreads();

    int gid = blockIdx.x * 256 + threadIdx.x;
    int v = gid >> 5, ch = threadIdx.x & 31;
    if (v >= nV) return;

    float x = (ch < ND) ? xv[(size_t)v * ND + ch] : 0.f;
    float t = sb1[ch];
#pragma unroll
    for (int i = 0; i < ND; i++) t = fmaf(__shfl(x, i, 32), sF[i * 32 + ch], t);

    float agr[HD], ahr[HD];
    {
        const float4* pg4 = reinterpret_cast<const float4*>(Ag + (size_t)v * HD);
        const float4* ph4 = reinterpret_cast<const float4*>(Ah + (size_t)v * HD);
#pragma unroll
        for (int q = 0; q < 8; q++) {
            float4 a = pg4[q];
            agr[4*q+0] = a.x; agr[4*q+1] = a.y; agr[4*q+2] = a.z; agr[4*q+3] = a.w;
            float4 b = ph4[q];
            ahr[4*q+0] = b.x; ahr[4*q+1] = b.y; ahr[4*q+2] = b.z; ahr[4*q+3] = b.w;
        }
    }
    float sg = 0.f, sh = 0.f;
#pragma unroll
    for (int c = 0; c < HD; c++) {
        sg = fmaf(agr[c], sMg[c * 32 + ch], sg);
        sh = fmaf(ahr[c], sMh[c * 32 + ch], sh);
    }
    int dg = deg_g[v], dh = deg_h[v];
    float invg = dg > 0 ? 1.f / (float)dg : 0.f;
    float invh = dh > 0 ? 1.f / (float)dh : 0.f;
    t += (dg > 0 ? sbg[ch] : 0.f) + (dh > 0 ? sbh[ch] : 0.f) + invg * sg + invh * sh;
    float hid = fmaxf(t, 0.f);

    float pf = sbf[ch];
#pragma unroll
    for (int h = 0; h < HD; h++) pf = fmaf(__shfl(hid, h, 32), sN[h * 32 + ch], pf);
    float hi = __shfl_xor(pf, 1, 32);
    if (!(ch & 1)) PFga16[(size_t)v * 16 + (ch >> 1)] = packbf2(pf, hi);
}

// ===========================================================================
// ga edge kernel: one wave (64 lanes) per cut node, lane = edge-slot.
// ===========================================================================
__global__ __launch_bounds__(256) void ga_edge_kernel(
    const float* __restrict__ PXga, const unsigned* __restrict__ PFga16,
    const int2* __restrict__ slot_a, const float* __restrict__ ea_a,
    const int* __restrict__ off_a, const int* __restrict__ deg_a,
    const float* __restrict__ gaW1,
    float* __restrict__ Aga, int nA)
{
    int gid = blockIdx.x * 256 + threadIdx.x;
    int a   = gid >> 6;
    int ln  = threadIdx.x & 63;
    if (a >= nA) return;

    float px[HD], acc[HD];
    {
        const float4* pp = reinterpret_cast<const float4*>(PXga + (size_t)a * HD);
#pragma unroll
        for (int q = 0; q < 8; q++) {
            float4 t = pp[q];
            px[4*q+0] = t.x; px[4*q+1] = t.y; px[4*q+2] = t.z; px[4*q+3] = t.w;
        }
    }
#pragma unroll
    for (int ch = 0; ch < HD; ch++) acc[ch] = 0.f;

    int base = off_a[a], d = deg_a[a];
    for (int k = ln; k < d; k += 64) {
        int2 w = slot_a[base + k];
        int t = w.x, e = w.y;
        const uint4* pr = reinterpret_cast<const uint4*>(PFga16 + (size_t)t * 16);
        uint4 r0 = pr[0], r1 = pr[1], r2 = pr[2], r3 = pr[3];
        const float4* pe = reinterpret_cast<const float4*>(ea_a + (size_t)e * ED);
        float4 q0 = pe[0], q1 = pe[1];
        float pf[HD], ev[ED];
        unpack8(r0, pf + 0); unpack8(r1, pf + 8);
        unpack8(r2, pf + 16); unpack8(r3, pf + 24);
        ev[0]=q0.x; ev[1]=q0.y; ev[2]=q0.z; ev[3]=q0.w;
        ev[4]=q1.x; ev[5]=q1.y; ev[6]=q1.z; ev[7]=q1.w;
#pragma unroll
        for (int ch = 0; ch < HD; ch++) {
            float t2 = px[ch] + pf[ch];
#pragma unroll
            for (int i = 0; i < ED; i++) t2 = fmaf(ev[i], gaW1[(ND + HD + i) * HD + ch], t2);
            acc[ch] += fmaxf(t2, 0.f);
        }
    }
#pragma unroll
    for (int m = 1; m < 64; m <<= 1) {
#pragma unroll
        for (int ch = 0; ch < HD; ch++) acc[ch] += __shfl_xor(acc[ch], m, 64);
    }
    if (ln == 0) {
        float4* dst = reinterpret_cast<float4*>(Aga + (size_t)a * HD);
#pragma unroll
        for (int q = 0; q < 8; q++)
            dst[q] = make_float4(acc[4*q+0], acc[4*q+1], acc[4*q+2], acc[4*q+3]);
    }
}

// ===========================================================================
// fa node kernel, CHANNEL-PARALLEL: thread = (a, ch) -> final output.
// ===========================================================================
__global__ __launch_bounds__(256) void fa_node_kernel(
    const float* __restrict__ xa,
    const float* __restrict__ Aga, const int* __restrict__ deg_a,
    const float* __restrict__ faW1, const float* __restrict__ fab1,
    const float* __restrict__ faW2, const float* __restrict__ fab2,
    const float* __restrict__ Mga, const float* __restrict__ bga,
    float* __restrict__ out, int nA)
{
    __shared__ float sM[1024], sW2[1024], sF[512];
    __shared__ float sbga[32], sb1[32], sb2[32];
    for (int i = threadIdx.x; i < 1024; i += 256) { sM[i] = Mga[i]; sW2[i] = faW2[i]; }
    for (int i = threadIdx.x; i < 512; i += 256) sF[i] = faW1[i];
    if (threadIdx.x < 32) {
        sbga[threadIdx.x] = bga[threadIdx.x];
        sb1[threadIdx.x]  = fab1[threadIdx.x];
        sb2[threadIdx.x]  = fab2[threadIdx.x];
    }
    __syncthreads();

    int gid = blockIdx.x * 256 + threadIdx.x;
    int a = gid >> 5, ch = threadIdx.x & 31;
    if (a >= nA) return;

    float x = (ch < ND) ? xa[(size_t)a * ND + ch] : 0.f;
    float t = sb1[ch];
#pragma unroll
    for (int i = 0; i < ND; i++) t = fmaf(__shfl(x, i, 32), sF[i * 32 + ch], t);

    float agr[HD];
    {
        const float4* pg4 = reinterpret_cast<const float4*>(Aga + (size_t)a * HD);
#pragma unroll
        for (int q = 0; q < 8; q++) {
            float4 w = pg4[q];
            agr[4*q+0] = w.x; agr[4*q+1] = w.y; agr[4*q+2] = w.z; agr[4*q+3] = w.w;
        }
    }
    float s = 0.f;
#pragma unroll
    for (int c = 0; c < HD; c++) s = fmaf(agr[c], sM[c * 32 + ch], s);
    int d = deg_a[a];
    float inv = d > 0 ? 1.f / (float)d : 0.f;
    t += (d > 0 ? sbga[ch] : 0.f) + inv * s;
    float hid = fmaxf(t, 0.f);

    float o = sb2[ch];
#pragma unroll
    for (int h = 0; h < HD; h++) o = fmaf(__shfl(hid, h, 32), sW2[h * 32 + ch], o);
    out[(size_t)a * HD + ch] = o;
}

// ===========================================================================
extern "C" void kernel_launch(void* const* d_in, const int* in_sizes, int n_in,
                              void* d_out, int out_size, void* d_ws, size_t ws_size,
                              hipStream_t stream) {
    const float* x_c    = (const float*)d_in[0];
    const float* x_v    = (const float*)d_in[1];
    const float* x_a    = (const float*)d_in[2];
    const int*   ei_c2v = (const int*)d_in[3];
    const int*   ei_a2v = (const int*)d_in[4];
    const float* ea_c2v = (const float*)d_in[5];
    const float* ea_a2v = (const float*)d_in[6];
    const float *gv_W1=(const float*)d_in[7],  *gv_b1=(const float*)d_in[8],
                *gv_W2=(const float*)d_in[9],  *gv_b2=(const float*)d_in[10];
    const float *hv_W1=(const float*)d_in[11], *hv_b1=(const float*)d_in[12],
                *hv_W2=(const float*)d_in[13], *hv_b2=(const float*)d_in[14];
    const float *fv_W1=(const float*)d_in[15], *fv_b1=(const float*)d_in[16],
                *fv_W2=(const float*)d_in[17], *fv_b2=(const float*)d_in[18];
    const float *ga_W1=(const float*)d_in[19], *ga_b1=(const float*)d_in[20],
                *ga_W2=(const float*)d_in[21], *ga_b2=(const float*)d_in[22];
    const float *fa_W1=(const float*)d_in[23], *fa_b1=(const float*)d_in[24],
                *fa_W2=(const float*)d_in[25], *fa_b2=(const float*)d_in[26];

    const int NC = in_sizes[0] / ND;
    const int NV = in_sizes[1] / ND;
    const int NA = in_sizes[2] / ND;
    const int EC = in_sizes[3] / 2;
    const int EA = in_sizes[4] / 2;
    (void)n_in; (void)out_size;

    const int* c2v_s = ei_c2v;            // constraint side of c2v
    const int* c2v_t = ei_c2v + EC;       // variable side
    const int* a2v_s = ei_a2v;            // cut node side
    const int* a2v_t = ei_a2v + EA;       // variable side

    const int chunksV = (NV + 1023) / 1024;
    const int chunksA = (NA + 1023) / 1024;
    const int csizeV = (NV + NPART - 1) / NPART;   // must be <= MAXCSV
    const int csizeA = (NA + NPART - 1) / NPART;   // must be <= MAXCSA

    // pick nch=64 if workspace fits, else 16 (layout computed per nch)
    int nch = 64;
    size_t fixedWords =
        (size_t)2 * (2 * NV + NA)            // deg + off
        + 3 * 1024                           // csum
        + 2 * (size_t)(EC + 2 * EA) + 2      // slots (+align)
        + (size_t)NV * HD * 5 + (size_t)NA * HD * 3  // PXg,PXh,Ag,Ah + PXga,Aga (approx upper)
        + (size_t)NC * 16 + (size_t)NA * 16  // PCg16, PAh16
        + 4 * HD * HD + 4 * HD;              // M's, b's
    {
        size_t cntW = (size_t)NPART * 64 * (2 * (size_t)csizeV + csizeA);
        if ((fixedWords + cntW) * 4 > ws_size) nch = 16;
    }

    // Workspace layout (4B words)
    int* wsI = (int*)d_ws;
    int* deg_g = wsI;                 // NV
    int* deg_h = deg_g + NV;          // NV
    int* deg_a = deg_h + NV;          // NA
    int* off_g = deg_a + NA;          // NV
    int* off_h = off_g + NV;          // NV
    int* off_a = off_h + NV;          // NA
    int* csum_g = off_a + NA;         // 1024
    int* csum_h = csum_g + 1024;      // 1024
    int* csum_a = csum_h + 1024;      // 1024
    int* cnt_g = csum_a + 1024;                        // NPART*nch*csizeV
    int* cnt_h = cnt_g + (size_t)NPART * nch * csizeV; // NPART*nch*csizeV
    int* cnt_a = cnt_h + (size_t)NPART * nch * csizeV; // NPART*nch*csizeA
    int* endcnt = cnt_a + (size_t)NPART * nch * csizeA;
    size_t words = (size_t)(endcnt - wsI);
    if (words & 1) words++;                            // 8B-align slots
    int2* slot_g = (int2*)(wsI + words);    // EC
    int2* slot_h = slot_g + EC;             // EA
    int2* slot_a = slot_h + EA;             // EA
    float* PXg = (float*)(slot_a + EA);     // NV*32 (aliased as PFga16 later)
    float* PXh = PXg + (size_t)NV * HD;     // NV*32
    float* PXga= PXh + (size_t)NV * HD;     // NA*32
    float* Ag  = PXga + (size_t)NA * HD;    // NV*32
    float* Ah  = Ag + (size_t)NV * HD;      // NV*32
    float* Aga = Ah + (size_t)NV * HD;      // NA*32
    unsigned* PCg16 = (unsigned*)(Aga + (size_t)NA * HD);  // NC*16
    unsigned* PAh16 = PCg16 + (size_t)NC * 16;             // NA*16
    float* Mg  = (float*)(PAh16 + (size_t)NA * 16);        // 1024
    float* Mh  = Mg + HD * HD;            // 1024
    float* Mga = Mh + HD * HD;            // 1024
    float* Nfv = Mga + HD * HD;           // 1024
    float* bgv = Nfv + HD * HD;           // 32
    float* bhv = bgv + HD;                // 32
    float* bgav= bhv + HD;                // 32
    float* bfv = bgav + HD;               // 32
    unsigned* PFga16 = (unsigned*)PXg;    // alias: PXg dead after fv_edge

    // standalone precompute (independent of CSR build)
    {
        int bV = (NV * 32 + 255) / 256, bC = (NC * 32 + 255) / 256, bA = (NA * 32 + 255) / 256;
        precompC_kernel<<<bV + bC + bA + 4, 256, 0, stream>>>(
            x_v, x_c, x_a,
            gv_W1, gv_b1, hv_W1, hv_b1, ga_W1, ga_b1,
            gv_W2, gv_b2, hv_W2, hv_b2, ga_W2, ga_b2,
            fv_W1, fv_W2, fv_b2, fa_W1,
            PXg, PXh, PXga, PCg16, PAh16,
            Mg, bgv, Mh, bhv, Mga, bgav, Nfv, bfv, NV, NC, NA);
    }

    // pass A: atomic-free LDS histograms -> per-(part,chunk) counts
    countP_kernel<<<2 * NPART * nch, 256, 0, stream>>>(
        c2v_t, cnt_g, EC, a2v_t, a2v_s, cnt_h, cnt_a, EA, csizeV, csizeA, nch);

    // deg = sum over chunks
    int degThreads = 2 * NV + NA;
    degsum_kernel<<<(degThreads + 255) / 256, 256, 0, stream>>>(
        cnt_g, cnt_h, cnt_a, deg_g, deg_h, deg_a, NV, NA, csizeV, csizeA, nch);

    // global exclusive scans -> off
    scan_p1f<<<2 * chunksV + chunksA, 256, 0, stream>>>(
        deg_g, deg_h, deg_a, csum_g, csum_h, csum_a, NV, NA, chunksV);
    scan_p2<<<3, 1024, 0, stream>>>(csum_g, chunksV, csum_h, chunksV, csum_a, chunksA);
    scan_p3f<<<2 * chunksV + chunksA, 1024, 0, stream>>>(
        deg_g, deg_h, deg_a, csum_g, csum_h, csum_a,
        off_g, off_h, off_a, NV, NA, chunksV);

    // per-(chunk,node) write bases (in place over cnt arrays)
    chunkbase_kernel<<<(degThreads + 255) / 256, 256, 0, stream>>>(
        cnt_g, cnt_h, cnt_a, off_g, off_h, off_a, NV, NA, csizeV, csizeA, nch);

    // pass B: atomic-free scatter (LDS slot assignment, XCD-local writes)
    scatterB_kernel<<<2 * NPART * nch, 256, 0, stream>>>(
        c2v_t, c2v_s, cnt_g, slot_g, EC,
        a2v_t, a2v_s, cnt_h, cnt_a, slot_h, slot_a, EA, csizeV, csizeA, nch);

    // variable-node edge aggregation (8 lanes/node)
    fv_edge_kernel<<<(NV * 8 + 255) / 256, 256, 0, stream>>>(
        PXg, PCg16, PXh, PAh16, slot_g, slot_h, ea_c2v, ea_a2v,
        off_g, deg_g, off_h, deg_h, gv_W1, hv_W1, Ag, Ah, NV);

    // variable-node MLP -> PFga16 (channel-parallel; f_v folded into ga partial)
    fv_node_kernel<<<(NV * 32 + 255) / 256, 256, 0, stream>>>(
        x_v, Ag, Ah, deg_g, deg_h,
        fv_W1, fv_b1, Mg, bgv, Mh, bhv, Nfv, bfv, PFga16, NV);

    // cut-node edge aggregation (64 lanes/node)
    ga_edge_kernel<<<(NA * 64 + 255) / 256, 256, 0, stream>>>(
        PXga, PFga16, slot_a, ea_a2v,
        off_a, deg_a, ga_W1, Aga, NA);

    // cut-node MLP -> output (channel-parallel)
    fa_node_kernel<<<(NA * 32 + 255) / 256, 256, 0, stream>>>(
        x_a, Aga, deg_a,
        fa_W1, fa_b1, fa_W2, fa_b2, Mga, bgav, (float*)d_out, NA);
}